// Round 1
// baseline (1524.653 us; speedup 1.0000x reference)
//
#include <hip/hip_runtime.h>
#include <math.h>

// Problem constants (fixed by setup_inputs)
#define BB 8
#define SS 1024
#define DD 512
#define HH 8
#define CC 64
#define PP 2047   // 2S-1

// ---------------------------------------------------------------------------
// Generic tiled fp32 GEMM: Y = X[M,512] @ W[512,512] (+bias), scatter per MODE
// MODE 0: QKV proj -> Y[b][h][s][c]   (B,H,S,C) layout, with bias
// MODE 1: pos proj -> Y[h][u][c]      (H,P,C) layout, no bias
// MODE 2: out proj -> Y[row][col]     plain row-major, with bias
// Block: 64x64 tile, 256 threads, 4x4 per thread, BK=16.
// ---------------------------------------------------------------------------
template <int MODE>
__global__ __launch_bounds__(256) void gemm_proj(
    const float* __restrict__ X, const float* __restrict__ W,
    const float* __restrict__ bias, float* __restrict__ Y, int M)
{
    __shared__ float As[16][68];  // [k][m] transposed
    __shared__ float Bs[16][68];  // [k][n]

    const int tid = threadIdx.x;
    const int tx = tid & 15, ty = tid >> 4;
    const int n0 = blockIdx.x * 64;
    const int m0 = blockIdx.y * 64;

    const int lm  = tid >> 2;          // 0..63  (X row within tile)
    const int lk4 = (tid & 3) * 4;     // 0,4,8,12
    const int lkw = tid >> 4;          // 0..15  (W k-row)
    const int lnw = (tid & 15) * 4;    // 0..60  (W col)

    float acc[4][4] = {};

    for (int k0 = 0; k0 < DD; k0 += 16) {
        // X tile -> As (transposed)
        float4 xv = make_float4(0.f, 0.f, 0.f, 0.f);
        int row = m0 + lm;
        if (row < M) xv = *(const float4*)(X + (size_t)row * DD + k0 + lk4);
        As[lk4 + 0][lm] = xv.x;
        As[lk4 + 1][lm] = xv.y;
        As[lk4 + 2][lm] = xv.z;
        As[lk4 + 3][lm] = xv.w;
        // W tile -> Bs
        float4 wv = *(const float4*)(W + (size_t)(k0 + lkw) * DD + n0 + lnw);
        *(float4*)&Bs[lkw][lnw] = wv;
        __syncthreads();
        #pragma unroll
        for (int kk = 0; kk < 16; ++kk) {
            float4 a = *(const float4*)&As[kk][ty * 4];
            float4 b = *(const float4*)&Bs[kk][tx * 4];
            float ar[4] = {a.x, a.y, a.z, a.w};
            float br[4] = {b.x, b.y, b.z, b.w};
            #pragma unroll
            for (int i = 0; i < 4; ++i)
                #pragma unroll
                for (int j = 0; j < 4; ++j)
                    acc[i][j] += ar[i] * br[j];
        }
        __syncthreads();
    }

    #pragma unroll
    for (int i = 0; i < 4; ++i) {
        int row = m0 + ty * 4 + i;
        if (row >= M) continue;
        int col = n0 + tx * 4;
        float4 o;
        o.x = acc[i][0]; o.y = acc[i][1]; o.z = acc[i][2]; o.w = acc[i][3];
        if (MODE != 1) {
            o.x += bias[col];
            o.y += bias[col + 1];
            o.z += bias[col + 2];
            o.w += bias[col + 3];
        }
        if (MODE == 0) {
            int b = row >> 10, s = row & 1023;
            int h = col >> 6, c = col & 63;
            *(float4*)&Y[(((size_t)b * HH + h) * SS + s) * CC + c] = o;
        } else if (MODE == 1) {
            int h = col >> 6, c = col & 63;
            *(float4*)&Y[((size_t)h * PP + row) * CC + c] = o;
        } else {
            *(float4*)&Y[(size_t)row * DD + col] = o;
        }
    }
}

// ---------------------------------------------------------------------------
// Score kernel: scores[bb,h,s,t] = (q_u[s]·k[t] + q_v[s]·p[S-1+t-s]) / 8
// with mask -> -inf. One block computes a 64x64 (s,t) tile for one (b,h).
// grid: x = t-tile (16), y = s-tile (16), z = bb*H + h
// ---------------------------------------------------------------------------
__global__ __launch_bounds__(256) void score_kernel(
    const float* __restrict__ q, const float* __restrict__ k,
    const float* __restrict__ p, const float* __restrict__ ub,
    const float* __restrict__ vbias, const unsigned char* __restrict__ mask,
    float* __restrict__ scores, int b0)
{
    const int h  = blockIdx.z & 7;
    const int bb = blockIdx.z >> 3;   // local batch idx within chunk
    const int b  = b0 + bb;
    const int t0 = blockIdx.x * 64;
    const int s0 = blockIdx.y * 64;

    __shared__ float Qu[16][68];
    __shared__ float Qv[16][68];
    __shared__ float Ks[16][68];
    __shared__ float Ps[16][132];   // p band: 127 rows

    const int tid = threadIdx.x;
    const int tx = tid & 15, ty = tid >> 4;
    const int lm  = tid >> 2;
    const int lk4 = (tid & 3) * 4;

    const float* qbase = q + ((size_t)b * HH + h) * SS * CC;
    const float* kbase = k + ((size_t)b * HH + h) * SS * CC;
    const float* pbase = p + (size_t)h * PP * CC;
    const int pb = (SS - 1) + t0 - s0 - 63;   // band start row in p (always >= 0)

    float acc[4][4] = {};

    for (int k0 = 0; k0 < CC; k0 += 16) {
        // Q tile (+u / +v bias) -> Qu/Qv transposed [k][m]
        float4 q4 = *(const float4*)(qbase + (size_t)(s0 + lm) * CC + k0 + lk4);
        #pragma unroll
        for (int j = 0; j < 4; ++j) {
            float x = ((const float*)&q4)[j];
            Qu[lk4 + j][lm] = x + ub[h * CC + k0 + lk4 + j];
            Qv[lk4 + j][lm] = x + vbias[h * CC + k0 + lk4 + j];
        }
        // K tile -> Ks [k][t]
        float4 k4 = *(const float4*)(kbase + (size_t)(t0 + lm) * CC + k0 + lk4);
        #pragma unroll
        for (int j = 0; j < 4; ++j) Ks[lk4 + j][lm] = ((const float*)&k4)[j];
        // p band rows 0..126 -> Ps [k][u]
        #pragma unroll
        for (int uu = 0; uu < 2; ++uu) {
            int u = uu * 64 + lm;
            if (u < 127) {
                float4 p4 = *(const float4*)(pbase + (size_t)(pb + u) * CC + k0 + lk4);
                #pragma unroll
                for (int j = 0; j < 4; ++j) Ps[lk4 + j][u] = ((const float*)&p4)[j];
            }
        }
        __syncthreads();
        #pragma unroll
        for (int kk = 0; kk < 16; ++kk) {
            float4 a  = *(const float4*)&Qu[kk][ty * 4];
            float4 av = *(const float4*)&Qv[kk][ty * 4];
            float4 bk = *(const float4*)&Ks[kk][tx * 4];
            float ar[4] = {a.x, a.y, a.z, a.w};
            float vr[4] = {av.x, av.y, av.z, av.w};
            float br[4] = {bk.x, bk.y, bk.z, bk.w};
            #pragma unroll
            for (int i = 0; i < 4; ++i) {
                int ubase = tx * 4 - (ty * 4 + i) + 63;
                #pragma unroll
                for (int j = 0; j < 4; ++j) {
                    acc[i][j] += ar[i] * br[j] + vr[i] * Ps[kk][ubase + j];
                }
            }
        }
        __syncthreads();
    }

    // epilogue: scale, mask, store
    #pragma unroll
    for (int i = 0; i < 4; ++i) {
        float4 o;
        float* op = &o.x;
        #pragma unroll
        for (int j = 0; j < 4; ++j) {
            float v = acc[i][j] * 0.125f;   // 1/sqrt(64)
            if (mask[b * SS + t0 + tx * 4 + j]) v = -INFINITY;
            op[j] = v;
        }
        *(float4*)&scores[(((size_t)bb * HH + h) * SS + (s0 + ty * 4 + i)) * SS + t0 + tx * 4] = o;
    }
}

// ---------------------------------------------------------------------------
// Row softmax over 1024 elements, in place. One block (256 thr) per row.
// ---------------------------------------------------------------------------
__global__ __launch_bounds__(256) void softmax_kernel(float* __restrict__ scores)
{
    const size_t row = blockIdx.x;
    float* r = scores + row * SS;
    const int tid = threadIdx.x;

    float4 v = *(float4*)(r + tid * 4);
    float m = fmaxf(fmaxf(v.x, v.y), fmaxf(v.z, v.w));
    #pragma unroll
    for (int off = 32; off; off >>= 1) m = fmaxf(m, __shfl_down(m, off, 64));
    __shared__ float redm[4];
    __shared__ float reds[4];
    if ((tid & 63) == 0) redm[tid >> 6] = m;
    __syncthreads();
    m = fmaxf(fmaxf(redm[0], redm[1]), fmaxf(redm[2], redm[3]));

    v.x = __expf(v.x - m);
    v.y = __expf(v.y - m);
    v.z = __expf(v.z - m);
    v.w = __expf(v.w - m);
    float s = v.x + v.y + v.z + v.w;
    #pragma unroll
    for (int off = 32; off; off >>= 1) s += __shfl_down(s, off, 64);
    if ((tid & 63) == 0) reds[tid >> 6] = s;
    __syncthreads();
    s = reds[0] + reds[1] + reds[2] + reds[3];

    float inv = 1.0f / s;
    v.x *= inv; v.y *= inv; v.z *= inv; v.w *= inv;
    *(float4*)(r + tid * 4) = v;
}

// ---------------------------------------------------------------------------
// PV: x[b,s,h*C+c] = sum_t P[s,t] * V[b,h,t,c].  M=1024, N=64, K=1024.
// grid: y = s-tile (16), z = bb*H + h
// ---------------------------------------------------------------------------
__global__ __launch_bounds__(256) void pv_kernel(
    const float* __restrict__ scores, const float* __restrict__ v,
    float* __restrict__ x, int b0)
{
    const int h  = blockIdx.z & 7;
    const int bb = blockIdx.z >> 3;
    const int b  = b0 + bb;
    const int s0 = blockIdx.y * 64;

    const float* P_ = scores + ((size_t)bb * HH + h) * SS * SS;
    const float* V_ = v + ((size_t)b * HH + h) * SS * CC;

    __shared__ float As[16][68];  // P transposed [k][m]
    __shared__ float Bs[16][68];  // V [k][c]

    const int tid = threadIdx.x;
    const int tx = tid & 15, ty = tid >> 4;
    const int lm  = tid >> 2;
    const int lk4 = (tid & 3) * 4;
    const int lkw = tid >> 4;
    const int lnw = (tid & 15) * 4;

    float acc[4][4] = {};

    for (int k0 = 0; k0 < SS; k0 += 16) {
        float4 a4 = *(const float4*)(P_ + (size_t)(s0 + lm) * SS + k0 + lk4);
        As[lk4 + 0][lm] = a4.x;
        As[lk4 + 1][lm] = a4.y;
        As[lk4 + 2][lm] = a4.z;
        As[lk4 + 3][lm] = a4.w;
        float4 b4 = *(const float4*)(V_ + (size_t)(k0 + lkw) * CC + lnw);
        *(float4*)&Bs[lkw][lnw] = b4;
        __syncthreads();
        #pragma unroll
        for (int kk = 0; kk < 16; ++kk) {
            float4 a = *(const float4*)&As[kk][ty * 4];
            float4 bv = *(const float4*)&Bs[kk][tx * 4];
            float ar[4] = {a.x, a.y, a.z, a.w};
            float br[4] = {bv.x, bv.y, bv.z, bv.w};
            #pragma unroll
            for (int i = 0; i < 4; ++i)
                #pragma unroll
                for (int j = 0; j < 4; ++j)
                    acc[i][j] += ar[i] * br[j];
        }
        __syncthreads();
    }

    #pragma unroll
    for (int i = 0; i < 4; ++i) {
        float4 o;
        o.x = acc[i][0]; o.y = acc[i][1]; o.z = acc[i][2]; o.w = acc[i][3];
        *(float4*)&x[((size_t)b * SS + (s0 + ty * 4 + i)) * DD + h * CC + tx * 4] = o;
    }
}

// ---------------------------------------------------------------------------
extern "C" void kernel_launch(void* const* d_in, const int* in_sizes, int n_in,
                              void* d_out, int out_size, void* d_ws, size_t ws_size,
                              hipStream_t stream)
{
    (void)in_sizes; (void)n_in; (void)out_size;

    const float* query = (const float*)d_in[0];
    const float* key_  = (const float*)d_in[1];
    const float* value = (const float*)d_in[2];
    const float* pos   = (const float*)d_in[3];
    const unsigned char* mask = (const unsigned char*)d_in[4];
    const float* Wq   = (const float*)d_in[5];
    const float* bq   = (const float*)d_in[6];
    const float* Wk   = (const float*)d_in[7];
    const float* bk   = (const float*)d_in[8];
    const float* Wv   = (const float*)d_in[9];
    const float* bv   = (const float*)d_in[10];
    const float* Wpos = (const float*)d_in[11];
    const float* Wout = (const float*)d_in[12];
    const float* bout = (const float*)d_in[13];
    const float* ub   = (const float*)d_in[14];
    const float* vb   = (const float*)d_in[15];

    float* ws = (float*)d_ws;
    const size_t NQKV = (size_t)BB * HH * SS * CC;  // 4194304
    const size_t NP   = (size_t)HH * PP * CC;       // 1048064
    const size_t NX   = (size_t)BB * SS * DD;       // 4194304

    float* qb   = ws;
    float* kb   = qb + NQKV;
    float* vbuf = kb + NQKV;
    float* pb   = vbuf + NQKV;
    float* xb   = pb + NP;
    float* sc   = xb + NX;

    const size_t base_floats = 3 * NQKV + NP + NX;
    const size_t full_sc = (size_t)BB * HH * SS * SS;   // 64M floats
    const bool full = (ws_size / 4 >= base_floats + full_sc);

    dim3 blk(256);

    gemm_proj<0><<<dim3(8, 128), blk, 0, stream>>>(query, Wq, bq, qb, BB * SS);
    gemm_proj<0><<<dim3(8, 128), blk, 0, stream>>>(key_, Wk, bk, kb, BB * SS);
    gemm_proj<0><<<dim3(8, 128), blk, 0, stream>>>(value, Wv, bv, vbuf, BB * SS);
    gemm_proj<1><<<dim3(8, 32), blk, 0, stream>>>(pos, Wpos, nullptr, pb, PP);

    const int nbatch = full ? BB : 1;
    for (int b0 = 0; b0 < BB; b0 += nbatch) {
        score_kernel<<<dim3(16, 16, nbatch * HH), blk, 0, stream>>>(
            qb, kb, pb, ub, vb, mask, sc, b0);
        softmax_kernel<<<dim3(nbatch * HH * SS), blk, 0, stream>>>(sc);
        pv_kernel<<<dim3(1, 16, nbatch * HH), blk, 0, stream>>>(sc, vbuf, xb, b0);
    }

    gemm_proj<2><<<dim3(8, 128), blk, 0, stream>>>(xb, Wout, bout, (float*)d_out, BB * SS);
}

// Round 2
// 364.212 us; speedup vs baseline: 4.1862x; 4.1862x over previous
//
#include <hip/hip_runtime.h>
#include <math.h>

typedef unsigned short ushort_t;
typedef __attribute__((ext_vector_type(8))) short short8;
typedef __attribute__((ext_vector_type(4))) float f32x4;

#define MFMA(a,b,c) __builtin_amdgcn_mfma_f32_16x16x32_bf16((a),(b),(c),0,0,0)

// Problem constants
#define BB 8
#define SS 1024
#define DD 512
#define HH 8
#define CC 64
#define PP 2047   // 2S-1

static __device__ __forceinline__ ushort_t f2bf(float f) {
    unsigned u = __float_as_uint(f);
    u += 0x7fffu + ((u >> 16) & 1u);       // RNE
    return (ushort_t)(u >> 16);
}
static __device__ __forceinline__ float bf2f(ushort_t h) {
    return __uint_as_float(((unsigned)h) << 16);
}
static __device__ __forceinline__ unsigned pack2(float a, float b) {
    return (unsigned)f2bf(a) | ((unsigned)f2bf(b) << 16);
}

// ---------------------------------------------------------------------------
// Cast kernel: fp32->bf16 for q/k/v/pos; transpose+cast for the 5 weights.
// blocks [0,3072): q/k/v, [3072,3328): pos, [3328,3648): weight transpose
// ---------------------------------------------------------------------------
__global__ __launch_bounds__(256) void cast_kernel(
    const float* __restrict__ q, const float* __restrict__ k,
    const float* __restrict__ v, const float* __restrict__ pos,
    const float* __restrict__ Wq, const float* __restrict__ Wk,
    const float* __restrict__ Wv, const float* __restrict__ Wp,
    const float* __restrict__ Wo,
    ushort_t* __restrict__ xq, ushort_t* __restrict__ xk,
    ushort_t* __restrict__ xv, ushort_t* __restrict__ xpos,
    ushort_t* __restrict__ wt)
{
    __shared__ float T[64][65];
    const int bid = blockIdx.x, tid = threadIdx.x;
    if (bid < 3328) {
        const float* src; ushort_t* dst; size_t n; int lb;
        if (bid < 1024)      { src = q;   dst = xq;   n = 4194304; lb = bid; }
        else if (bid < 2048) { src = k;   dst = xk;   n = 4194304; lb = bid - 1024; }
        else if (bid < 3072) { src = v;   dst = xv;   n = 4194304; lb = bid - 2048; }
        else                 { src = pos; dst = xpos; n = 1048064; lb = bid - 3072; }
        size_t off = (size_t)lb * 4096 + (size_t)tid * 16;
        if (off < n) {
            float4 f0 = *(const float4*)(src + off);
            float4 f1 = *(const float4*)(src + off + 4);
            float4 f2 = *(const float4*)(src + off + 8);
            float4 f3 = *(const float4*)(src + off + 12);
            uint4 u0, u1;
            u0.x = pack2(f0.x, f0.y); u0.y = pack2(f0.z, f0.w);
            u0.z = pack2(f1.x, f1.y); u0.w = pack2(f1.z, f1.w);
            u1.x = pack2(f2.x, f2.y); u1.y = pack2(f2.z, f2.w);
            u1.z = pack2(f3.x, f3.y); u1.w = pack2(f3.z, f3.w);
            *(uint4*)(dst + off)     = u0;
            *(uint4*)(dst + off + 8) = u1;
        }
    } else {
        const int wi   = (bid - 3328) >> 6;      // which weight
        const int tile = (bid - 3328) & 63;
        const float* Wsrc = (wi == 0) ? Wq : (wi == 1) ? Wk : (wi == 2) ? Wv
                          : (wi == 3) ? Wp : Wo;
        ushort_t* Wdst = wt + (size_t)wi * 262144;
        const int tk0 = (tile >> 3) * 64, tn0 = (tile & 7) * 64;
        const int r = tid >> 2, c4 = (tid & 3) * 16;
        #pragma unroll
        for (int rep = 0; rep < 4; ++rep) {
            float4 f = *(const float4*)(Wsrc + (size_t)(tk0 + r) * 512 + tn0 + c4 + rep * 4);
            T[r][c4 + rep * 4 + 0] = f.x; T[r][c4 + rep * 4 + 1] = f.y;
            T[r][c4 + rep * 4 + 2] = f.z; T[r][c4 + rep * 4 + 3] = f.w;
        }
        __syncthreads();
        #pragma unroll
        for (int rep = 0; rep < 4; ++rep) {
            uint2 u;
            u.x = pack2(T[c4 + rep * 4 + 0][r], T[c4 + rep * 4 + 1][r]);
            u.y = pack2(T[c4 + rep * 4 + 2][r], T[c4 + rep * 4 + 3][r]);
            *(uint2*)(Wdst + (size_t)(tn0 + r) * 512 + tk0 + c4 + rep * 4) = u;
        }
    }
}

// ---------------------------------------------------------------------------
// MFMA projection GEMM: Y = X[M,512] @ Wt^T (+bias), bf16 in, per-MODE out.
// MODE 0: Q -> qu,qv bf16 [B,H,S,C] (adds bq then u/v bias)
// MODE 1/2: K/V -> bf16 [B,H,S,C] (adds bias)
// MODE 3: pos -> bf16 [H,P,C] (no bias; M=2047 guarded)
// MODE 4: out-proj -> fp32 row-major (adds bias)
// Block: 128(M) x 64(N) tile, 256 thr (4 waves), BK=64.
// ---------------------------------------------------------------------------
template<int MODE>
__global__ __launch_bounds__(256) void proj_kernel(
    const ushort_t* __restrict__ X, const ushort_t* __restrict__ W,
    const float* __restrict__ b1, const float* __restrict__ b2,
    const float* __restrict__ b3,
    ushort_t* __restrict__ Y1, ushort_t* __restrict__ Y2,
    float* __restrict__ Yf)
{
    __shared__ __align__(16) ushort_t Xs[128][72];
    __shared__ __align__(16) ushort_t Ws[64][72];
    const int tid = threadIdx.x;
    const int wave = tid >> 6, lane = tid & 63, quad = lane >> 4, l16 = lane & 15;
    const int n0 = blockIdx.x * 64, m0 = blockIdx.y * 128;

    f32x4 acc[2][4];
    #pragma unroll
    for (int i = 0; i < 2; ++i)
        #pragma unroll
        for (int j = 0; j < 4; ++j) acc[i][j] = (f32x4){0.f, 0.f, 0.f, 0.f};

    for (int k0 = 0; k0 < 512; k0 += 64) {
        #pragma unroll
        for (int i = 0; i < 4; ++i) {
            int c = tid + 256 * i; int r = c >> 3; int cc = (c & 7) * 8;
            int gr = m0 + r;
            if (MODE == 3 && gr > 2046) gr = 2046;
            *(uint4*)&Xs[r][cc] = *(const uint4*)(X + (size_t)gr * 512 + k0 + cc);
        }
        #pragma unroll
        for (int i = 0; i < 2; ++i) {
            int c = tid + 256 * i; int r = c >> 3; int cc = (c & 7) * 8;
            *(uint4*)&Ws[r][cc] = *(const uint4*)(W + (size_t)(n0 + r) * 512 + k0 + cc);
        }
        __syncthreads();
        #pragma unroll
        for (int kk = 0; kk < 2; ++kk) {
            short8 a0 = *(const short8*)&Xs[wave * 32 + l16][kk * 32 + quad * 8];
            short8 a1 = *(const short8*)&Xs[wave * 32 + 16 + l16][kk * 32 + quad * 8];
            #pragma unroll
            for (int ns = 0; ns < 4; ++ns) {
                short8 bf = *(const short8*)&Ws[ns * 16 + l16][kk * 32 + quad * 8];
                acc[0][ns] = MFMA(a0, bf, acc[0][ns]);
                acc[1][ns] = MFMA(a1, bf, acc[1][ns]);
            }
        }
        __syncthreads();
    }

    #pragma unroll
    for (int ms = 0; ms < 2; ++ms)
    #pragma unroll
    for (int ns = 0; ns < 4; ++ns)
    #pragma unroll
    for (int r = 0; r < 4; ++r) {
        const int row = m0 + wave * 32 + ms * 16 + quad * 4 + r;
        const int col = n0 + ns * 16 + l16;
        const float v = acc[ms][ns][r];
        if (MODE == 0) {
            float base = v + b1[col];
            size_t idx = (((size_t)(row >> 10) * HH + (col >> 6)) * SS + (row & 1023)) * CC + (col & 63);
            Y1[idx] = f2bf(base + b2[col]);
            Y2[idx] = f2bf(base + b3[col]);
        } else if (MODE == 1 || MODE == 2) {
            size_t idx = (((size_t)(row >> 10) * HH + (col >> 6)) * SS + (row & 1023)) * CC + (col & 63);
            Y1[idx] = f2bf(v + b1[col]);
        } else if (MODE == 3) {
            if (row < PP)
                Y1[((size_t)(col >> 6) * PP + row) * CC + (col & 63)] = f2bf(v);
        } else {
            Yf[(size_t)row * 512 + col] = v + b1[col];
        }
    }
}

// ---------------------------------------------------------------------------
// Fused rel-pos flash attention. One block = (b, h, 64 s-rows); 4 waves,
// wave w owns s rows [s0+16w, s0+16w+16). Iterates 16 t-tiles of 64.
//   AC  = q_u . K^T           (MFMA)
//   BD  = gather of band GEMM q_v . p_band^T  (MFMA + LDS shift)
//   online softmax (m,l per row), PV via MFMA with V^T staged in LDS.
// ---------------------------------------------------------------------------
__global__ __launch_bounds__(256) void attn_kernel(
    const ushort_t* __restrict__ qu_g, const ushort_t* __restrict__ qv_g,
    const ushort_t* __restrict__ kb, const ushort_t* __restrict__ vbf,
    const ushort_t* __restrict__ pbf, const unsigned char* __restrict__ mask,
    ushort_t* __restrict__ xg)
{
    const int s0 = blockIdx.x * 64;
    const int bh = blockIdx.y;            // b*8 + h
    const int b = bh >> 3, h = bh & 7;
    const int tid = threadIdx.x;
    const int wave = tid >> 6, lane = tid & 63, quad = lane >> 4, l16 = lane & 15;

    __shared__ __align__(16) ushort_t Ks[64][72];
    __shared__ __align__(16) ushort_t Vt[64][72];     // transposed: Vt[c][t]
    __shared__ __align__(16) ushort_t Pb[128][72];    // p band
    __shared__ __align__(16) ushort_t Bscr[4][16][80];// per-wave band (bf16)
    __shared__ __align__(16) ushort_t Pscr[4][16 * 72];// per-wave P re-layout

    // Q fragments (A-operand, m = lane&15), loaded once
    const size_t qoff = ((size_t)bh * SS + s0 + wave * 16 + l16) * CC;
    short8 quA[2], qvA[2];
    quA[0] = *(const short8*)(qu_g + qoff + quad * 8);
    quA[1] = *(const short8*)(qu_g + qoff + 32 + quad * 8);
    qvA[0] = *(const short8*)(qv_g + qoff + quad * 8);
    qvA[1] = *(const short8*)(qv_g + qoff + 32 + quad * 8);

    f32x4 O[4];
    #pragma unroll
    for (int i = 0; i < 4; ++i) O[i] = (f32x4){0.f, 0.f, 0.f, 0.f};
    float mrow[4] = {-1e30f, -1e30f, -1e30f, -1e30f};
    float lrow[4] = {0.f, 0.f, 0.f, 0.f};

    const ushort_t* pbase = pbf + (size_t)h * PP * CC;
    const int uw0 = 48 - wave * 16;

    for (int t0 = 0; t0 < SS; t0 += 64) {
        // ---- stage K, V^T, p band ----
        const ushort_t* kbase = kb  + ((size_t)bh * SS + t0) * CC;
        const ushort_t* vbase = vbf + ((size_t)bh * SS + t0) * CC;
        #pragma unroll
        for (int i = 0; i < 2; ++i) {
            int c = tid + 256 * i; int r = c >> 3; int cc = (c & 7) * 8;
            *(uint4*)&Ks[r][cc] = *(const uint4*)(kbase + r * 64 + cc);
        }
        #pragma unroll
        for (int i = 0; i < 2; ++i) {
            int c = tid + 256 * i; int r = c >> 3; int cc = (c & 7) * 8;
            uint4 d = *(const uint4*)(vbase + r * 64 + cc);
            const ushort_t* dp = (const ushort_t*)&d;
            #pragma unroll
            for (int j = 0; j < 8; ++j) {
                int jj = (j + (cc >> 3)) & 7;   // bank-swizzled scalar scatter
                Vt[cc + jj][r] = dp[jj];
            }
        }
        const int ubp = 1023 + t0 - s0 - 63;   // band start row in p (>= 0)
        #pragma unroll
        for (int i = 0; i < 4; ++i) {
            int c = tid + 256 * i; int r = c >> 3; int cc = (c & 7) * 8;
            int gu = ubp + r; if (gu > PP - 1) gu = PP - 1;
            *(uint4*)&Pb[r][cc] = *(const uint4*)(pbase + (size_t)gu * 64 + cc);
        }
        __syncthreads();

        // ---- AC = q_u . K^T ----
        f32x4 ac[4];
        #pragma unroll
        for (int ns = 0; ns < 4; ++ns) {
            ac[ns] = (f32x4){0.f, 0.f, 0.f, 0.f};
            #pragma unroll
            for (int kk = 0; kk < 2; ++kk) {
                short8 bf = *(const short8*)&Ks[ns * 16 + l16][kk * 32 + quad * 8];
                ac[ns] = MFMA(quA[kk], bf, ac[ns]);
            }
        }
        // ---- band = q_v . p_band^T (wave-local 16 x 80) ----
        f32x4 bd[5];
        #pragma unroll
        for (int us = 0; us < 5; ++us) {
            bd[us] = (f32x4){0.f, 0.f, 0.f, 0.f};
            #pragma unroll
            for (int kk = 0; kk < 2; ++kk) {
                short8 pf = *(const short8*)&Pb[uw0 + us * 16 + l16][kk * 32 + quad * 8];
                bd[us] = MFMA(qvA[kk], pf, bd[us]);
            }
        }
        // write band to wave-private scratch (bf16)
        #pragma unroll
        for (int us = 0; us < 5; ++us)
            #pragma unroll
            for (int r = 0; r < 4; ++r)
                Bscr[wave][quad * 4 + r][us * 16 + l16] = f2bf(bd[us][r]);

        // ---- shift-gather + scale + mask ----
        float pv[4][4];
        #pragma unroll
        for (int ns = 0; ns < 4; ++ns) {
            const int t = t0 + ns * 16 + l16;
            const bool mk = mask[b * SS + t] != 0;
            #pragma unroll
            for (int r = 0; r < 4; ++r) {
                const int sl = quad * 4 + r;
                float bdv = bf2f(Bscr[wave][sl][ns * 16 + l16 + 15 - sl]);
                float scv = (ac[ns][r] + bdv) * 0.125f;
                pv[ns][r] = mk ? -1e30f : scv;
            }
        }
        // ---- online softmax (rows live in quads: 16 lanes per row) ----
        #pragma unroll
        for (int r = 0; r < 4; ++r) {
            float mx = fmaxf(fmaxf(pv[0][r], pv[1][r]), fmaxf(pv[2][r], pv[3][r]));
            mx = fmaxf(mx, __shfl_xor(mx, 1));
            mx = fmaxf(mx, __shfl_xor(mx, 2));
            mx = fmaxf(mx, __shfl_xor(mx, 4));
            mx = fmaxf(mx, __shfl_xor(mx, 8));
            const float mnew = fmaxf(mrow[r], mx);
            const float alpha = __expf(mrow[r] - mnew);
            mrow[r] = mnew;
            float s = 0.f;
            #pragma unroll
            for (int ns = 0; ns < 4; ++ns) {
                float p = __expf(pv[ns][r] - mnew);
                pv[ns][r] = p; s += p;
            }
            s += __shfl_xor(s, 1); s += __shfl_xor(s, 2);
            s += __shfl_xor(s, 4); s += __shfl_xor(s, 8);
            lrow[r] = lrow[r] * alpha + s;
            #pragma unroll
            for (int ns = 0; ns < 4; ++ns) O[ns][r] *= alpha;
        }
        // ---- P: C/D layout -> A layout via wave-private LDS ----
        ushort_t* Ps = Pscr[wave];
        #pragma unroll
        for (int ns = 0; ns < 4; ++ns)
            #pragma unroll
            for (int r = 0; r < 4; ++r)
                Ps[(quad * 4 + r) * 72 + ns * 16 + l16] = f2bf(pv[ns][r]);
        short8 pA0 = *(const short8*)(Ps + l16 * 72 + quad * 8);
        short8 pA1 = *(const short8*)(Ps + l16 * 72 + 32 + quad * 8);
        // ---- O += P . V ----
        #pragma unroll
        for (int ns = 0; ns < 4; ++ns) {
            short8 v0 = *(const short8*)&Vt[ns * 16 + l16][quad * 8];
            short8 v1 = *(const short8*)&Vt[ns * 16 + l16][32 + quad * 8];
            O[ns] = MFMA(pA0, v0, O[ns]);
            O[ns] = MFMA(pA1, v1, O[ns]);
        }
        __syncthreads();
    }

    // ---- finalize: O /= l, write x bf16 [B,S,D] ----
    #pragma unroll
    for (int r = 0; r < 4; ++r) {
        const float inv = 1.0f / lrow[r];
        const int s = s0 + wave * 16 + quad * 4 + r;
        #pragma unroll
        for (int ns = 0; ns < 4; ++ns) {
            const int c = ns * 16 + l16;
            xg[((size_t)b * SS + s) * DD + h * CC + c] = f2bf(O[ns][r] * inv);
        }
    }
}

// ---------------------------------------------------------------------------
extern "C" void kernel_launch(void* const* d_in, const int* in_sizes, int n_in,
                              void* d_out, int out_size, void* d_ws, size_t ws_size,
                              hipStream_t stream)
{
    (void)in_sizes; (void)n_in; (void)out_size; (void)ws_size;

    const float* query = (const float*)d_in[0];
    const float* key_  = (const float*)d_in[1];
    const float* value = (const float*)d_in[2];
    const float* pos   = (const float*)d_in[3];
    const unsigned char* mask = (const unsigned char*)d_in[4];
    const float* Wq   = (const float*)d_in[5];
    const float* bq   = (const float*)d_in[6];
    const float* Wk   = (const float*)d_in[7];
    const float* bk   = (const float*)d_in[8];
    const float* Wv   = (const float*)d_in[9];
    const float* bv   = (const float*)d_in[10];
    const float* Wpos = (const float*)d_in[11];
    const float* Wout = (const float*)d_in[12];
    const float* bout = (const float*)d_in[13];
    const float* ub   = (const float*)d_in[14];
    const float* vb   = (const float*)d_in[15];

    const size_t NBS = (size_t)BB * SS * DD;   // 4194304
    const size_t NP  = (size_t)PP * DD;        // 1048064 (== H*P*C)
    const size_t NW  = (size_t)DD * DD;        // 262144

    ushort_t* xq   = (ushort_t*)d_ws;
    ushort_t* xk   = xq + NBS;
    ushort_t* xv   = xk + NBS;
    ushort_t* xpos = xv + NBS;
    ushort_t* wt   = xpos + NP;                // 5 transposed weights
    ushort_t* qu   = wt + 5 * NW;
    ushort_t* qv   = qu + NBS;
    ushort_t* kbuf = qv + NBS;
    ushort_t* vbuf = kbuf + NBS;
    ushort_t* pbuf = vbuf + NBS;               // NP elems
    ushort_t* xg   = pbuf + NP;

    ushort_t* WtQ = wt;
    ushort_t* WtK = wt + NW;
    ushort_t* WtV = wt + 2 * NW;
    ushort_t* WtP = wt + 3 * NW;
    ushort_t* WtO = wt + 4 * NW;

    dim3 blk(256);

    cast_kernel<<<dim3(3648), blk, 0, stream>>>(
        query, key_, value, pos, Wq, Wk, Wv, Wpos, Wout,
        xq, xk, xv, xpos, wt);

    proj_kernel<0><<<dim3(8, 64), blk, 0, stream>>>(xq, WtQ, bq, ub, vb, qu, qv, nullptr);
    proj_kernel<1><<<dim3(8, 64), blk, 0, stream>>>(xk, WtK, bk, nullptr, nullptr, kbuf, nullptr, nullptr);
    proj_kernel<2><<<dim3(8, 64), blk, 0, stream>>>(xv, WtV, bv, nullptr, nullptr, vbuf, nullptr, nullptr);
    proj_kernel<3><<<dim3(8, 16), blk, 0, stream>>>(xpos, WtP, nullptr, nullptr, nullptr, pbuf, nullptr, nullptr);

    attn_kernel<<<dim3(16, 64), blk, 0, stream>>>(qu, qv, kbuf, vbuf, pbuf, mask, xg);

    proj_kernel<4><<<dim3(8, 64), blk, 0, stream>>>(xg, WtO, bout, nullptr, nullptr, nullptr, nullptr, (float*)d_out);
}